// Round 2
// baseline (9454.888 us; speedup 1.0000x reference)
//
#include <hip/hip_runtime.h>
#include <hip/hip_bf16.h>

// FPS (farthest point sampling) + gather for B=8, N=16384, C=256, m=N/4.
//
// Exactness strategy: the reference (JAX/NumPy) computes
//   d = ((dx*dx + dy*dy) + dz*dz)   with NO fma contraction,
//   dist = min(dist, d), next = argmax(dist) (FIRST max index).
// We replicate that bit-exactly: contract(off) on the distance, and a
// (value, first-index) tie-break comparator through all reduce levels.
//
// Structure: one 1024-thread block per batch (FPS is sequential over m-1
// iterations; cross-block sync is more expensive than one CU's compute).
// Each thread owns 16 points in registers (px/py/pz/dist). Per iteration:
//   - 16-pt min-update + local argmax (12 VALU/pt, ~1536 cyc/CU)
//   - wave shfl_xor argmax reduce (6 steps)
//   - ONE __syncthreads with double-buffered LDS partials; every wave
//     redundantly reduces the 16 wave-partials (no second barrier)
//   - winner coords re-loaded from pos via wave-uniform load (L2-hot)

constexpr int NPTS   = 16384;
constexpr int PTS    = 16;      // points per thread
constexpr int FPS_T  = 1024;    // threads per block
constexpr int WAVES  = FPS_T / 64;

__global__ __launch_bounds__(FPS_T) void fps_kernel(
    const float* __restrict__ pos,   // [B, N, 3]
    float* __restrict__ pos_out,     // [B, m, 3]
    int* __restrict__ idx_out,       // [B, m] in workspace
    int m)
{
    const int b    = blockIdx.x;
    const int t    = threadIdx.x;
    const int lane = t & 63;
    const int wid  = t >> 6;
    const float* posb = pos + (size_t)b * NPTS * 3;

    float px[PTS], py[PTS], pz[PTS], dist[PTS];
    const int base = t * PTS;
#pragma unroll
    for (int j = 0; j < PTS; ++j) {
        px[j]   = posb[(base + j) * 3 + 0];
        py[j]   = posb[(base + j) * 3 + 1];
        pz[j]   = posb[(base + j) * 3 + 2];
        dist[j] = 1e10f;
    }

    // double-buffered per-wave partials: one barrier per iteration is safe
    // (write slot s&1, barrier, read slot s&1; next write goes to the other
    // slot, and a same-slot rewrite is always two barriers past any reader)
    __shared__ float s_v[2][WAVES];
    __shared__ int   s_i[2][WAVES];

    float lx = posb[0], ly = posb[1], lz = posb[2];

    if (t == 0) {
        idx_out[(size_t)b * m] = 0;
        pos_out[((size_t)b * m) * 3 + 0] = lx;
        pos_out[((size_t)b * m) * 3 + 1] = ly;
        pos_out[((size_t)b * m) * 3 + 2] = lz;
    }

    for (int s = 1; s < m; ++s) {
        float bv = -1.0f;
        int   bj = 0;
        {
#pragma clang fp contract(off)
#pragma unroll
            for (int j = 0; j < PTS; ++j) {
                float dx = px[j] - lx;
                float dy = py[j] - ly;
                float dz = pz[j] - lz;
                float d  = ((dx * dx) + (dy * dy)) + (dz * dz);  // ref order, no fma
                float nd = fminf(dist[j], d);
                dist[j]  = nd;
                if (nd > bv) { bv = nd; bj = j; }  // strict > keeps FIRST max (ascending j)
            }
        }
        int bi = base + bj;

        // wave-level argmax (total order => all 64 lanes converge to winner)
#pragma unroll
        for (int mask = 32; mask >= 1; mask >>= 1) {
            float ov = __shfl_xor(bv, mask);
            int   oi = __shfl_xor(bi, mask);
            if (ov > bv || (ov == bv && oi < bi)) { bv = ov; bi = oi; }
        }

        const int buf = s & 1;
        if (lane == 0) { s_v[buf][wid] = bv; s_i[buf][wid] = bi; }
        __syncthreads();

        // every wave redundantly reduces the 16 wave-partials (no 2nd barrier)
        float gv = s_v[buf][lane & (WAVES - 1)];
        int   gi = s_i[buf][lane & (WAVES - 1)];
#pragma unroll
        for (int mask = WAVES / 2; mask >= 1; mask >>= 1) {
            float ov = __shfl_xor(gv, mask);
            int   oi = __shfl_xor(gi, mask);
            if (ov > gv || (ov == gv && oi < gi)) { gv = ov; gi = oi; }
        }

        // winner coords via wave-uniform load (pos is L2-resident, 192 KB/batch)
        int gis = __builtin_amdgcn_readfirstlane(gi);
        lx = posb[gis * 3 + 0];
        ly = posb[gis * 3 + 1];
        lz = posb[gis * 3 + 2];

        if (t == 0) {
            idx_out[(size_t)b * m + s] = gis;
            pos_out[((size_t)b * m + s) * 3 + 0] = lx;
            pos_out[((size_t)b * m + s) * 3 + 1] = ly;
            pos_out[((size_t)b * m + s) * 3 + 2] = lz;
        }
    }
}

// feat gather: one wave per output row, 256 floats = 64 lanes x float4
__global__ __launch_bounds__(256) void gather_kernel(
    const float* __restrict__ feat,   // [B, N, C]
    const int*   __restrict__ idx,    // [B, m]
    float*       __restrict__ out,    // [B, m, C]
    int m, int C)
{
    const int wid  = threadIdx.x >> 6;
    const int lane = threadIdx.x & 63;
    const int r    = blockIdx.x * 4 + wid;     // row in [0, B*m)
    const int b    = r >> 12;                  // m = 4096
    const int src  = idx[r];
    const float4* sp = (const float4*)(feat + ((size_t)b * NPTS + src) * C);
    float4*       dp = (float4*)(out + (size_t)r * C);
    dp[lane] = sp[lane];
}

extern "C" void kernel_launch(void* const* d_in, const int* in_sizes, int n_in,
                              void* d_out, int out_size, void* d_ws, size_t ws_size,
                              hipStream_t stream) {
    const float* pos  = (const float*)d_in[0];   // [8, 16384, 3] f32
    const float* feat = (const float*)d_in[1];   // [8, 16384, 256] f32

    const int B = 8, C = 256;
    const int m = NPTS / 4;                      // 4096

    float* out_pos  = (float*)d_out;                          // [8, 4096, 3]
    float* out_feat = out_pos + (size_t)B * m * 3;            // [8, 4096, 256]
    int*   idx      = (int*)d_ws;                             // [8, 4096] = 128 KB

    fps_kernel<<<dim3(B), dim3(FPS_T), 0, stream>>>(pos, out_pos, idx, m);
    gather_kernel<<<dim3(B * m / 4), dim3(256), 0, stream>>>(feat, idx, out_feat, m, C);
}

// Round 3
// 9042.129 us; speedup vs baseline: 1.0456x; 1.0456x over previous
//
#include <hip/hip_runtime.h>
#include <hip/hip_bf16.h>

// FPS (farthest point sampling) + gather for B=8, N=16384, C=256, m=N/4.
//
// Exactness: reference computes d = ((dx*dx + dy*dy) + dz*dz) with NO fma
// contraction; dist = min(dist, d); argmax takes the FIRST max index. We
// replicate bit-exactly (contract(off) + (value, min-index) comparator at
// every reduce level). Validated absmax=0 in R2.
//
// R3 changes vs R2:
//  - __launch_bounds__(1024, 4): exactly 1 block/CU -> 128 VGPR/wave budget.
//    R2's 48-VGPR allocation meant px/py/pz were re-fetched from memory every
//    iteration (5450 cyc/iter). Pin them with empty asm "+v" so they stay
//    VGPR-resident (64 data regs + temps ~ 100 < 128).
//  - Replace ds_bpermute-based __shfl_xor argmax reduce (~30-40 cyc/step
//    serial) with VALU-pipe cross-lane: DPP quad_perm ^1/^2, half_mirror,
//    row_mirror, then v_permlane16/32_swap_b32 (gfx950). Comparator is a
//    commutative idempotent semilattice => any full-mixing network is exact.

constexpr int NPTS   = 16384;
constexpr int PTS    = 16;      // points per thread
constexpr int FPS_T  = 1024;    // threads per block
constexpr int WAVES  = FPS_T / 64;

template <int CTRL>
__device__ __forceinline__ float dpp_f(float x) {
    return __builtin_bit_cast(float,
        __builtin_amdgcn_update_dpp(0, __builtin_bit_cast(int, x), CTRL, 0xF, 0xF, true));
}
template <int CTRL>
__device__ __forceinline__ int dpp_i(int x) {
    return __builtin_amdgcn_update_dpp(0, x, CTRL, 0xF, 0xF, true);
}

// v_permlane16_swap_b32 a,b : per 32-lane half, a[16:31] <-> b[0:15].
// With a=b=v: a' = dup(v_lo16), b' = dup(v_hi16)  => neighbor(^16) =
// (lane&16) ? a' : b'.  Same pattern for 32 with (lane&32).
__device__ __forceinline__ void permswap16_f(float &a, float &b) {
    asm volatile("v_permlane16_swap_b32 %0, %1" : "+v"(a), "+v"(b));
}
__device__ __forceinline__ void permswap16_i(int &a, int &b) {
    asm volatile("v_permlane16_swap_b32 %0, %1" : "+v"(a), "+v"(b));
}
__device__ __forceinline__ void permswap32_f(float &a, float &b) {
    asm volatile("v_permlane32_swap_b32 %0, %1" : "+v"(a), "+v"(b));
}
__device__ __forceinline__ void permswap32_i(int &a, int &b) {
    asm volatile("v_permlane32_swap_b32 %0, %1" : "+v"(a), "+v"(b));
}

// (max value, min index on ties) -- select form to stay branchless
__device__ __forceinline__ void take(float &v, int &i, float ov, int oi) {
    bool t = (ov > v) || (ov == v && oi < i);
    v = t ? ov : v;
    i = t ? oi : i;
}

__global__ __launch_bounds__(FPS_T, 4) void fps_kernel(
    const float* __restrict__ pos,   // [B, N, 3]
    float* __restrict__ pos_out,     // [B, m, 3]
    int* __restrict__ idx_out,       // [B, m] in workspace
    int m)
{
    const int b    = blockIdx.x;
    const int t    = threadIdx.x;
    const int lane = t & 63;
    const int wid  = t >> 6;
    const bool l16 = (lane & 16) != 0;
    const bool l32 = (lane & 32) != 0;
    const float* posb = pos + (size_t)b * NPTS * 3;

    float px[PTS], py[PTS], pz[PTS], dist[PTS];
    const int base = t * PTS;
#pragma unroll
    for (int j = 0; j < PTS; ++j) {
        px[j]   = posb[(base + j) * 3 + 0];
        py[j]   = posb[(base + j) * 3 + 1];
        pz[j]   = posb[(base + j) * 3 + 2];
        dist[j] = 1e10f;
    }
    // Pin coordinates in VGPRs: opaque to the compiler -> cannot rematerialize
    // from global memory inside the main loop.
#pragma unroll
    for (int j = 0; j < PTS; ++j)
        asm volatile("" : "+v"(px[j]), "+v"(py[j]), "+v"(pz[j]));

    // double-buffered per-wave partials: one barrier per iteration is safe
    __shared__ float s_v[2][WAVES];
    __shared__ int   s_i[2][WAVES];

    float lx = posb[0], ly = posb[1], lz = posb[2];

    if (t == 0) {
        idx_out[(size_t)b * m] = 0;
        pos_out[((size_t)b * m) * 3 + 0] = lx;
        pos_out[((size_t)b * m) * 3 + 1] = ly;
        pos_out[((size_t)b * m) * 3 + 2] = lz;
    }

    for (int s = 1; s < m; ++s) {
        float bv = -1.0f;
        int   bj = 0;
        {
#pragma clang fp contract(off)
#pragma unroll
            for (int j = 0; j < PTS; ++j) {
                float dx = px[j] - lx;
                float dy = py[j] - ly;
                float dz = pz[j] - lz;
                float d  = ((dx * dx) + (dy * dy)) + (dz * dz);  // ref order, no fma
                float nd = fminf(dist[j], d);
                dist[j]  = nd;
                if (nd > bv) { bv = nd; bj = j; }  // strict > => FIRST max (ascending j)
            }
        }
        int bi = base + bj;

        // ---- wave argmax: VALU-pipe mixing network (exact semilattice) ----
        take(bv, bi, dpp_f<0xB1>(bv),  dpp_i<0xB1>(bi));   // quad_perm ^1
        take(bv, bi, dpp_f<0x4E>(bv),  dpp_i<0x4E>(bi));   // quad_perm ^2
        take(bv, bi, dpp_f<0x141>(bv), dpp_i<0x141>(bi));  // half_mirror (^7)
        take(bv, bi, dpp_f<0x140>(bv), dpp_i<0x140>(bi));  // row_mirror (^15)
        {   // ^16 via permlane16_swap
            float a = bv, c = bv; permswap16_f(a, c);
            int   e = bi, f = bi; permswap16_i(e, f);
            take(bv, bi, l16 ? a : c, l16 ? e : f);
        }
        {   // ^32 via permlane32_swap
            float a = bv, c = bv; permswap32_f(a, c);
            int   e = bi, f = bi; permswap32_i(e, f);
            take(bv, bi, l32 ? a : c, l32 ? e : f);
        }

        const int buf = s & 1;
        if (lane == 0) { s_v[buf][wid] = bv; s_i[buf][wid] = bi; }
        __syncthreads();

        // ---- block stage: every wave redundantly reduces 16 partials ----
        float gv = s_v[buf][lane & (WAVES - 1)];
        int   gi = s_i[buf][lane & (WAVES - 1)];
        take(gv, gi, dpp_f<0xB1>(gv),  dpp_i<0xB1>(gi));
        take(gv, gi, dpp_f<0x4E>(gv),  dpp_i<0x4E>(gi));
        take(gv, gi, dpp_f<0x141>(gv), dpp_i<0x141>(gi));
        take(gv, gi, dpp_f<0x140>(gv), dpp_i<0x140>(gi));

        // winner coords via wave-uniform scalar load (pos L2-resident)
        int gis = __builtin_amdgcn_readfirstlane(gi);
        lx = posb[gis * 3 + 0];
        ly = posb[gis * 3 + 1];
        lz = posb[gis * 3 + 2];

        if (t == 0) {
            idx_out[(size_t)b * m + s] = gis;
            pos_out[((size_t)b * m + s) * 3 + 0] = lx;
            pos_out[((size_t)b * m + s) * 3 + 1] = ly;
            pos_out[((size_t)b * m + s) * 3 + 2] = lz;
        }
    }
}

// feat gather: one wave per output row, 256 floats = 64 lanes x float4
__global__ __launch_bounds__(256) void gather_kernel(
    const float* __restrict__ feat,   // [B, N, C]
    const int*   __restrict__ idx,    // [B, m]
    float*       __restrict__ out,    // [B, m, C]
    int m, int C)
{
    const int wid  = threadIdx.x >> 6;
    const int lane = threadIdx.x & 63;
    const int r    = blockIdx.x * 4 + wid;     // row in [0, B*m)
    const int b    = r >> 12;                  // m = 4096
    const int src  = idx[r];
    const float4* sp = (const float4*)(feat + ((size_t)b * NPTS + src) * C);
    float4*       dp = (float4*)(out + (size_t)r * C);
    dp[lane] = sp[lane];
}

extern "C" void kernel_launch(void* const* d_in, const int* in_sizes, int n_in,
                              void* d_out, int out_size, void* d_ws, size_t ws_size,
                              hipStream_t stream) {
    const float* pos  = (const float*)d_in[0];   // [8, 16384, 3] f32
    const float* feat = (const float*)d_in[1];   // [8, 16384, 256] f32

    const int B = 8, C = 256;
    const int m = NPTS / 4;                      // 4096

    float* out_pos  = (float*)d_out;                          // [8, 4096, 3]
    float* out_feat = out_pos + (size_t)B * m * 3;            // [8, 4096, 256]
    int*   idx      = (int*)d_ws;                             // [8, 4096] = 128 KB

    fps_kernel<<<dim3(B), dim3(FPS_T), 0, stream>>>(pos, out_pos, idx, m);
    gather_kernel<<<dim3(B * m / 4), dim3(256), 0, stream>>>(feat, idx, out_feat, m, C);
}